// Round 4
// baseline (262.287 us; speedup 1.0000x reference)
//
#include <hip/hip_runtime.h>
#include <stdint.h>

#define MDIM 4096
#define NDIM 4096
#define KDIM 4096
#define BM 128
#define BN 128
#define BKB 128   // K-bytes (int8 elems) per tile step

typedef int i32x4 __attribute__((ext_vector_type(4)));

typedef __attribute__((address_space(1))) const void gv_t;
typedef __attribute__((address_space(3))) void lv_t;

__device__ __forceinline__ int pack4(int a, int b, int c, int d) {
    return (a & 0xFF) | ((b & 0xFF) << 8) | ((c & 0xFF) << 16) | ((d & 0xFF) << 24);
}

// pack int32 -> int8 with subtracted zero-point (zp read from device scalar)
__global__ void pack_x_kernel(const int* __restrict__ x, const int* __restrict__ zp_p,
                              int* __restrict__ out, int total16) {
    const int zp = zp_p[0];
    int idx = blockIdx.x * blockDim.x + threadIdx.x;
    int stride = gridDim.x * blockDim.x;
    for (int i = idx; i < total16; i += stride) {
        const int4* src = (const int4*)(x + (long)i * 16);
        int4 a = src[0], b = src[1], c = src[2], d = src[3];
        int4 r;
        r.x = pack4(a.x - zp, a.y - zp, a.z - zp, a.w - zp);
        r.y = pack4(b.x - zp, b.y - zp, b.z - zp, b.w - zp);
        r.z = pack4(c.x - zp, c.y - zp, c.z - zp, c.w - zp);
        r.w = pack4(d.x - zp, d.y - zp, d.z - zp, d.w - zp);
        ((int4*)out)[i] = r;
    }
}

__global__ void pack_w_kernel(const int* __restrict__ w, int* __restrict__ out, int total16) {
    int idx = blockIdx.x * blockDim.x + threadIdx.x;
    int stride = gridDim.x * blockDim.x;
    for (int i = idx; i < total16; i += stride) {
        const int4* src = (const int4*)(w + (long)i * 16);
        int4 a = src[0], b = src[1], c = src[2], d = src[3];
        int4 r;
        r.x = pack4(a.x, a.y, a.z, a.w);
        r.y = pack4(b.x, b.y, b.z, b.w);
        r.z = pack4(c.x, c.y, c.z, c.w);
        r.w = pack4(d.x, d.y, d.z, d.w);
        ((int4*)out)[i] = r;
    }
}

// 128x128 tile i8 GEMM, B^T layout (both A[M][K], B[N][K] row-major int8).
// m97 structure: global_load_lds(16B) staging with pre-swizzled source,
// XOR-swizzled ds_read_b128, 16x16x64 i8 MFMA, fused quant epilogue.
__global__ __launch_bounds__(256)
void gemm_i8_kernel(const char* __restrict__ A8, const char* __restrict__ B8,
                    const float* __restrict__ bias,
                    const float* __restrict__ xs_p, const float* __restrict__ ws_p,
                    const float* __restrict__ os_p, const int* __restrict__ ozp_p,
                    int* __restrict__ out) {
    __shared__ char lsA[BM * BKB];
    __shared__ char lsB[BN * BKB];

    const int t = threadIdx.x;
    const int lane = t & 63;
    const int wave = t >> 6;
    const int wr = wave >> 1;    // 2x2 wave grid, each wave: 64x64 output
    const int wc = wave & 1;
    const long brow = (long)blockIdx.y * BM;
    const long bcol = (long)blockIdx.x * BN;

    i32x4 acc[4][4] = {};

    // staging chunk geometry: chunk c -> row = c>>3 (128B rows), slot = c&7 (16B)
    // LDS dest is linear (c*16); global source slot is pre-swizzled (slot ^ row&7)
    int st_row[4], st_off[4];
    #pragma unroll
    for (int i = 0; i < 4; ++i) {
        int c = t + i * 256;
        int r = c >> 3, s = c & 7;
        st_row[i] = r;
        st_off[i] = (s ^ (r & 7)) * 16;
    }

    for (int kt = 0; kt < KDIM; kt += BKB) {
        #pragma unroll
        for (int i = 0; i < 4; ++i) {
            int c16 = (t + i * 256) * 16;
            __builtin_amdgcn_global_load_lds(
                (gv_t*)(A8 + (brow + st_row[i]) * KDIM + kt + st_off[i]),
                (lv_t*)(lsA + c16), 16, 0, 0);
            __builtin_amdgcn_global_load_lds(
                (gv_t*)(B8 + (bcol + st_row[i]) * KDIM + kt + st_off[i]),
                (lv_t*)(lsB + c16), 16, 0, 0);
        }
        __syncthreads();

        // fragment loads: A row = lane&15 (+16*mi), k-slot = (lane>>4) within 64B half
        i32x4 af[4][2], bf[4][2];
        #pragma unroll
        for (int mi = 0; mi < 4; ++mi) {
            int row = wr * 64 + mi * 16 + (lane & 15);
            #pragma unroll
            for (int kk = 0; kk < 2; ++kk) {
                int ls = kk * 4 + (lane >> 4);           // logical 16B slot 0..7
                af[mi][kk] = *(const i32x4*)(lsA + row * BKB + ((ls ^ (row & 7)) * 16));
            }
        }
        #pragma unroll
        for (int ni = 0; ni < 4; ++ni) {
            int row = wc * 64 + ni * 16 + (lane & 15);
            #pragma unroll
            for (int kk = 0; kk < 2; ++kk) {
                int ls = kk * 4 + (lane >> 4);
                bf[ni][kk] = *(const i32x4*)(lsB + row * BKB + ((ls ^ (row & 7)) * 16));
            }
        }

        #pragma unroll
        for (int mi = 0; mi < 4; ++mi)
            #pragma unroll
            for (int ni = 0; ni < 4; ++ni) {
                acc[mi][ni] = __builtin_amdgcn_mfma_i32_16x16x64_i8(af[mi][0], bf[ni][0], acc[mi][ni], 0, 0, 0);
                acc[mi][ni] = __builtin_amdgcn_mfma_i32_16x16x64_i8(af[mi][1], bf[ni][1], acc[mi][ni], 0, 0, 0);
            }
        __syncthreads();
    }

    // epilogue: dequant + bias, requant round-half-even, clip, int32 store
    const float scale = xs_p[0] * ws_p[0];
    const float os = os_p[0];
    const int ozp = ozp_p[0];
    #pragma unroll
    for (int mi = 0; mi < 4; ++mi) {
        long row0 = brow + wr * 64 + mi * 16 + (lane >> 4) * 4;
        #pragma unroll
        for (int ni = 0; ni < 4; ++ni) {
            long col = bcol + wc * 64 + ni * 16 + (lane & 15);
            float bv = bias[col];
            #pragma unroll
            for (int r = 0; r < 4; ++r) {
                float y = (float)acc[mi][ni][r] * scale + bv;
                int q = (int)rintf(y / os) + ozp;
                q = q < 0 ? 0 : (q > 255 ? 255 : q);
                out[(row0 + r) * NDIM + col] = q;
            }
        }
    }
}

// insurance fallback if workspace is too small (should not trigger)
__global__ void naive_gemm_kernel(const int* __restrict__ x, const int* __restrict__ w,
                                  const float* __restrict__ bias,
                                  const float* __restrict__ xs_p, const int* __restrict__ xzp_p,
                                  const float* __restrict__ ws_p, const float* __restrict__ os_p,
                                  const int* __restrict__ ozp_p, int* __restrict__ out) {
    long idx = (long)blockIdx.x * blockDim.x + threadIdx.x;
    if (idx >= (long)MDIM * NDIM) return;
    int m = idx >> 12, n = idx & (NDIM - 1);
    const int4* xr = (const int4*)(x + (long)m * KDIM);
    const int4* wv = (const int4*)(w + (long)n * KDIM);
    const int zp = xzp_p[0];
    int acc = 0;
    for (int k = 0; k < KDIM / 4; ++k) {
        int4 a = xr[k], b = wv[k];
        acc += (a.x - zp) * b.x + (a.y - zp) * b.y + (a.z - zp) * b.z + (a.w - zp) * b.w;
    }
    float y = (float)acc * (xs_p[0] * ws_p[0]) + bias[n];
    int q = (int)rintf(y / os_p[0]) + ozp_p[0];
    out[idx] = q < 0 ? 0 : (q > 255 ? 255 : q);
}

extern "C" void kernel_launch(void* const* d_in, const int* in_sizes, int n_in,
                              void* d_out, int out_size, void* d_ws, size_t ws_size,
                              hipStream_t stream) {
    const int*   x_q  = (const int*)d_in[0];
    const int*   w_q  = (const int*)d_in[1];
    const float* bias = (const float*)d_in[2];
    const float* xs   = (const float*)d_in[3];
    const int*   xzp  = (const int*)d_in[4];
    const float* wsc  = (const float*)d_in[5];
    const float* osc  = (const float*)d_in[6];
    const int*   ozp  = (const int*)d_in[7];
    int* out = (int*)d_out;

    const size_t need = 2UL * MDIM * KDIM;  // 32 MB packed int8
    if (ws_size >= need) {
        char* A8 = (char*)d_ws;
        char* B8 = A8 + (size_t)MDIM * KDIM;
        const int total16 = MDIM * KDIM / 16;
        pack_x_kernel<<<2048, 256, 0, stream>>>(x_q, xzp, (int*)A8, total16);
        pack_w_kernel<<<2048, 256, 0, stream>>>(w_q, (int*)B8, total16);
        dim3 grid(NDIM / BN, MDIM / BM);
        gemm_i8_kernel<<<grid, 256, 0, stream>>>(A8, B8, bias, xs, wsc, osc, ozp, out);
    } else {
        long total = (long)MDIM * NDIM;
        naive_gemm_kernel<<<(total + 255) / 256, 256, 0, stream>>>(
            x_q, w_q, bias, xs, xzp, wsc, osc, ozp, out);
    }
}

// Round 5
// 236.450 us; speedup vs baseline: 1.1093x; 1.1093x over previous
//
#include <hip/hip_runtime.h>
#include <stdint.h>

#define MDIM 4096
#define NDIM 4096
#define KDIM 4096
#define BM 256
#define BN 256
#define BKB 128            // K-bytes (int8 elems) per tile step
#define NT (KDIM / BKB)    // 32 K-tiles

typedef int i32x4 __attribute__((ext_vector_type(4)));

typedef __attribute__((address_space(1))) const void gv_t;
typedef __attribute__((address_space(3))) void lv_t;

#define BAR() do { asm volatile("" ::: "memory"); __builtin_amdgcn_s_barrier(); asm volatile("" ::: "memory"); } while (0)

__device__ __forceinline__ int pack4(int a, int b, int c, int d) {
    return (a & 0xFF) | ((b & 0xFF) << 8) | ((c & 0xFF) << 16) | ((d & 0xFF) << 24);
}

// pack int32 -> int8, 1 int4 load -> 1 int store per thread (fully coalesced)
__global__ void pack_x_kernel(const int* __restrict__ x, const int* __restrict__ zp_p,
                              int* __restrict__ out, int total4) {
    const int zp = zp_p[0];
    int i = blockIdx.x * blockDim.x + threadIdx.x;
    if (i < total4) {
        int4 a = ((const int4*)x)[i];
        out[i] = pack4(a.x - zp, a.y - zp, a.z - zp, a.w - zp);
    }
}

__global__ void pack_w_kernel(const int* __restrict__ w, int* __restrict__ out, int total4) {
    int i = blockIdx.x * blockDim.x + threadIdx.x;
    if (i < total4) {
        int4 a = ((const int4*)w)[i];
        out[i] = pack4(a.x, a.y, a.z, a.w);
    }
}

// 256x256-tile i8 GEMM, 8-phase counted-vmcnt schedule (T3+T4+T5 port of the
// m201 bf16 template). A[M][K], B[N][K] row-major int8 (byte-identical tile
// geometry to the bf16 BK=64 template). LDS: per-operand 2-parity buffers,
// staged at half-tile (16 KB) granularity, 1 half per phase, vmcnt(8) once
// per K-tile (never 0 in steady state). 16B-slot XOR swizzle (HW-verified
// 0 conflicts in round 4) on both stage-source and ds_read.
__global__ __launch_bounds__(512, 2)
void gemm_i8_8ph(const char* __restrict__ A8, const char* __restrict__ B8,
                 const float* __restrict__ bias,
                 const float* __restrict__ xs_p, const float* __restrict__ ws_p,
                 const float* __restrict__ os_p, const int* __restrict__ ozp_p,
                 int* __restrict__ out) {
    __shared__ char lds[131072];   // A: [2][32KB] at 0, B: [2][32KB] at 64KB

    const int t = threadIdx.x;
    const int lane = t & 63;
    const int wave = t >> 6;       // 0..7
    const int wr = wave >> 2;      // 2 M-waves: rows wr*128..+127
    const int wc = wave & 3;       // 4 N-waves: cols wc*64..+63

    // XCD-aware bijective swizzle: nwg=256, 256%8==0
    int wg = blockIdx.x;
    int swz = (wg & 7) * (256 / 8) + (wg >> 3);
    const long brow = (long)(swz >> 4) * BM;
    const long bcol = (long)(swz & 15) * BN;

    i32x4 acc[8][4] = {};

    // stage one half-tile (16 KB): h = 0,1 -> A rows [h*128,+128); 2,3 -> B.
    // 2 global_load_lds x 16B per thread. LDS dest linear; source slot
    // pre-swizzled (slot ^ row&7) so swizzled ds_read sees correct bytes.
    auto STAGE_HALF = [&](int tt, int h) {
        if (tt >= NT) return;
        const int d = tt & 1;
        const char* src = (h < 2) ? A8 : B8;
        const long base_rc = (h < 2) ? brow : bcol;
        const int rh = h & 1;
        const int kt = tt * BKB;
        char* ldsbase = lds + ((h < 2) ? 0 : 65536) + d * 32768;
        #pragma unroll
        for (int j = 0; j < 2; ++j) {
            int chunk = rh * 1024 + t + j * 512;   // 16B chunk index in tile
            int row = chunk >> 3, slot = chunk & 7;
            __builtin_amdgcn_global_load_lds(
                (gv_t*)(src + (base_rc + row) * KDIM + kt + ((slot ^ (row & 7)) * 16)),
                (lv_t*)(ldsbase + chunk * 16), 16, 0, 0);
        }
    };

    // prologue: tile0 fully, tile1 h0-h2 (t1.h3 goes in P0 of tile 0)
    STAGE_HALF(0, 0); STAGE_HALF(0, 1); STAGE_HALF(0, 2); STAGE_HALF(0, 3);
    STAGE_HALF(1, 0); STAGE_HALF(1, 1); STAGE_HALF(1, 2);

    for (int tt = 0; tt < NT; ++tt) {
        const int d = tt & 1;
        const char* Ac = lds + d * 32768;
        const char* Bc = lds + 65536 + d * 32768;

        // ---------------- P0 ----------------
        STAGE_HALF(tt + 1, 3);
        // all 4 halves of tile tt+1 (8 loads) may stay in flight; everything
        // older (tile tt) must have landed. Last tile: drain.
        if (tt == NT - 1) asm volatile("s_waitcnt vmcnt(0)" ::: "memory");
        else              asm volatile("s_waitcnt vmcnt(8)" ::: "memory");
        BAR();   // all waves' tile-tt data now visible in LDS

        // all fragment ds_reads for tile tt (compiler inserts counted lgkm waits)
        i32x4 af[8][2], bf[4][2];
        #pragma unroll
        for (int mi = 0; mi < 8; ++mi) {
            int row = wr * 128 + mi * 16 + (lane & 15);
            #pragma unroll
            for (int kk = 0; kk < 2; ++kk) {
                int ls = kk * 4 + (lane >> 4);
                af[mi][kk] = *(const i32x4*)(Ac + row * BKB + ((ls ^ (row & 7)) * 16));
            }
        }
        #pragma unroll
        for (int ni = 0; ni < 4; ++ni) {
            int row = wc * 64 + ni * 16 + (lane & 15);
            #pragma unroll
            for (int kk = 0; kk < 2; ++kk) {
                int ls = kk * 4 + (lane >> 4);
                bf[ni][kk] = *(const i32x4*)(Bc + row * BKB + ((ls ^ (row & 7)) * 16));
            }
        }

        __builtin_amdgcn_s_setprio(1);
        #pragma unroll
        for (int mi = 0; mi < 4; ++mi)
            #pragma unroll
            for (int ni = 0; ni < 2; ++ni)
                #pragma unroll
                for (int kk = 0; kk < 2; ++kk)
                    acc[mi][ni] = __builtin_amdgcn_mfma_i32_16x16x64_i8(af[mi][kk], bf[ni][kk], acc[mi][ni], 0, 0, 0);
        __builtin_amdgcn_s_setprio(0);
        // all 24 ds_reads must be complete before anyone overwrites this parity
        asm volatile("s_waitcnt lgkmcnt(0)" ::: "memory");
        BAR();

        // ---------------- P1 ----------------
        STAGE_HALF(tt + 2, 0);
        BAR();
        __builtin_amdgcn_s_setprio(1);
        #pragma unroll
        for (int mi = 0; mi < 4; ++mi)
            #pragma unroll
            for (int ni = 2; ni < 4; ++ni)
                #pragma unroll
                for (int kk = 0; kk < 2; ++kk)
                    acc[mi][ni] = __builtin_amdgcn_mfma_i32_16x16x64_i8(af[mi][kk], bf[ni][kk], acc[mi][ni], 0, 0, 0);
        __builtin_amdgcn_s_setprio(0);
        BAR();

        // ---------------- P2 ----------------
        STAGE_HALF(tt + 2, 1);
        BAR();
        __builtin_amdgcn_s_setprio(1);
        #pragma unroll
        for (int mi = 4; mi < 8; ++mi)
            #pragma unroll
            for (int ni = 0; ni < 2; ++ni)
                #pragma unroll
                for (int kk = 0; kk < 2; ++kk)
                    acc[mi][ni] = __builtin_amdgcn_mfma_i32_16x16x64_i8(af[mi][kk], bf[ni][kk], acc[mi][ni], 0, 0, 0);
        __builtin_amdgcn_s_setprio(0);
        BAR();

        // ---------------- P3 ----------------
        STAGE_HALF(tt + 2, 2);
        BAR();
        __builtin_amdgcn_s_setprio(1);
        #pragma unroll
        for (int mi = 4; mi < 8; ++mi)
            #pragma unroll
            for (int ni = 2; ni < 4; ++ni)
                #pragma unroll
                for (int kk = 0; kk < 2; ++kk)
                    acc[mi][ni] = __builtin_amdgcn_mfma_i32_16x16x64_i8(af[mi][kk], bf[ni][kk], acc[mi][ni], 0, 0, 0);
        __builtin_amdgcn_s_setprio(0);
        BAR();
    }

    // epilogue: dequant + bias, requant round-half-even, clip, int32 store
    const float scale = xs_p[0] * ws_p[0];
    const float os = os_p[0];
    const int ozp = ozp_p[0];
    #pragma unroll
    for (int mi = 0; mi < 8; ++mi) {
        long row0 = brow + wr * 128 + mi * 16 + (lane >> 4) * 4;
        #pragma unroll
        for (int ni = 0; ni < 4; ++ni) {
            long col = bcol + wc * 64 + ni * 16 + (lane & 15);
            float bv = bias[col];
            #pragma unroll
            for (int r = 0; r < 4; ++r) {
                float y = (float)acc[mi][ni][r] * scale + bv;
                int q = (int)rintf(y / os) + ozp;
                q = q < 0 ? 0 : (q > 255 ? 255 : q);
                out[(row0 + r) * NDIM + col] = q;
            }
        }
    }
}

// insurance fallback if workspace is too small (should not trigger)
__global__ void naive_gemm_kernel(const int* __restrict__ x, const int* __restrict__ w,
                                  const float* __restrict__ bias,
                                  const float* __restrict__ xs_p, const int* __restrict__ xzp_p,
                                  const float* __restrict__ ws_p, const float* __restrict__ os_p,
                                  const int* __restrict__ ozp_p, int* __restrict__ out) {
    long idx = (long)blockIdx.x * blockDim.x + threadIdx.x;
    if (idx >= (long)MDIM * NDIM) return;
    int m = idx >> 12, n = idx & (NDIM - 1);
    const int4* xr = (const int4*)(x + (long)m * KDIM);
    const int4* wv = (const int4*)(w + (long)n * KDIM);
    const int zp = xzp_p[0];
    int acc = 0;
    for (int k = 0; k < KDIM / 4; ++k) {
        int4 a = xr[k], b = wv[k];
        acc += (a.x - zp) * b.x + (a.y - zp) * b.y + (a.z - zp) * b.z + (a.w - zp) * b.w;
    }
    float y = (float)acc * (xs_p[0] * ws_p[0]) + bias[n];
    int q = (int)rintf(y / os_p[0]) + ozp_p[0];
    out[idx] = q < 0 ? 0 : (q > 255 ? 255 : q);
}

extern "C" void kernel_launch(void* const* d_in, const int* in_sizes, int n_in,
                              void* d_out, int out_size, void* d_ws, size_t ws_size,
                              hipStream_t stream) {
    const int*   x_q  = (const int*)d_in[0];
    const int*   w_q  = (const int*)d_in[1];
    const float* bias = (const float*)d_in[2];
    const float* xs   = (const float*)d_in[3];
    const int*   xzp  = (const int*)d_in[4];
    const float* wsc  = (const float*)d_in[5];
    const float* osc  = (const float*)d_in[6];
    const int*   ozp  = (const int*)d_in[7];
    int* out = (int*)d_out;

    const size_t need = 2UL * MDIM * KDIM;  // 32 MB packed int8
    if (ws_size >= need) {
        char* A8 = (char*)d_ws;
        char* B8 = A8 + (size_t)MDIM * KDIM;
        const int total4 = MDIM * KDIM / 4;
        pack_x_kernel<<<total4 / 256, 256, 0, stream>>>(x_q, xzp, (int*)A8, total4);
        pack_w_kernel<<<total4 / 256, 256, 0, stream>>>(w_q, (int*)B8, total4);
        gemm_i8_8ph<<<(MDIM / BM) * (NDIM / BN), 512, 0, stream>>>(
            A8, B8, bias, xs, wsc, osc, ozp, out);
    } else {
        long total = (long)MDIM * NDIM;
        naive_gemm_kernel<<<(total + 255) / 256, 256, 0, stream>>>(
            x_q, w_q, bias, xs, xzp, wsc, osc, ozp, out);
    }
}